// Round 10
// baseline (122.199 us; speedup 1.0000x reference)
//
#include <hip/hip_runtime.h>
#include <math.h>

#define BDIM 8
#define CDIM 256
#define C4DIM 64
#define NDIM 2048
#define LOG2E_SQ 2.0813689810056077f
#define NEG_2LOG2E_SQ -4.1627379620112154f

typedef short bf16x8 __attribute__((ext_vector_type(8)));
typedef float f32x4 __attribute__((ext_vector_type(4)));

__device__ inline unsigned cvt_pk(float lo, float hi) {
  unsigned r;
  asm("v_cvt_pk_bf16_f32 %0, %1, %2" : "=v"(r) : "v"(lo), "v"(hi));
  return r;
}
__device__ inline float bflo(unsigned u) {
  u <<= 16; float f; __builtin_memcpy(&f, &u, 4); return f;
}
__device__ inline float bfhi(unsigned u) {
  u &= 0xffff0000u; float f; __builtin_memcpy(&f, &u, 4); return f;
}

// ---------------------------------------------------------------------------
// prep: [0,1024) castT x->xT bf16; [1024,1168) cast weights; 1168 zero bn sums
// ---------------------------------------------------------------------------
__global__ __launch_bounds__(256) void prep_kernel(const float* __restrict__ x,
                                                   const float* __restrict__ wq,
                                                   const float* __restrict__ wv,
                                                   const float* __restrict__ wt,
                                                   short* __restrict__ xT,
                                                   short* __restrict__ wqb,
                                                   short* __restrict__ wvb,
                                                   short* __restrict__ wtb,
                                                   float* __restrict__ bnsum) {
  __shared__ float tile[64][65];
  const int fb = blockIdx.x, t = threadIdx.x;
  if (fb < 1024) {
    const int b = fb >> 7, c0 = ((fb >> 5) & 3) * 64, n0 = (fb & 31) * 64;
    const int cl = t >> 2, ng = (t & 3) * 16;
#pragma unroll
    for (int kk = 0; kk < 4; ++kk) {
      float4 v = *(const float4*)&x[((size_t)(b * CDIM + c0 + cl)) * NDIM + n0 + ng + kk * 4];
      tile[cl][ng + kk * 4 + 0] = v.x; tile[cl][ng + kk * 4 + 1] = v.y;
      tile[cl][ng + kk * 4 + 2] = v.z; tile[cl][ng + kk * 4 + 3] = v.w;
    }
    __syncthreads();
    const int nl = t >> 2, cg = (t & 3) * 16;
    unsigned u[8];
#pragma unroll
    for (int e = 0; e < 8; ++e)
      u[e] = cvt_pk(tile[cg + 2 * e][nl], tile[cg + 2 * e + 1][nl]);
    short* dst = &xT[((size_t)b * NDIM + n0 + nl) * CDIM + c0 + cg];
    *(uint4*)&dst[0] = make_uint4(u[0], u[1], u[2], u[3]);
    *(uint4*)&dst[8] = make_uint4(u[4], u[5], u[6], u[7]);
  } else if (fb < 1168) {
    const int idx = ((fb - 1024) * 256 + t) * 4;
    const float* src; short* dst; int off;
    if (idx < 16384)      { src = wq; dst = wqb; off = idx; }
    else if (idx < 81920) { src = wv; dst = wvb; off = idx - 16384; }
    else                  { src = wt; dst = wtb; off = idx - 81920; }
    float4 v = *(const float4*)&src[off];
    *(uint2*)&dst[off] = make_uint2(cvt_pk(v.x, v.y), cvt_pk(v.z, v.w));
  } else {
    bnsum[t] = 0.f; bnsum[256 + t] = 0.f;
  }
}

// ---------------------------------------------------------------------------
// 128x128 MFMA GEMM body: OUT[b][c][n] (bf16) = W * X[b] + bias.
// STATS: fused BN partial sums via per-channel atomics.
// ---------------------------------------------------------------------------
template<bool STATS>
__device__ __forceinline__ void gemm128(const short* __restrict__ Wb,
                                        const short* __restrict__ Xt,
                                        const float* __restrict__ bias,
                                        short* __restrict__ OUT,
                                        float* __restrict__ bnsum,
                                        float* __restrict__ bnss,
                                        int b, int n0, int c0, int t) {
  const int w = t >> 6, l = t & 63, il = l & 15, g = l >> 4;
  const int wn = w & 1, wc = w >> 1;
  const size_t arow = (size_t)b * NDIM + n0 + wn * 64;
  const int ccol = c0 + wc * 64;
  f32x4 acc[4][4] = {};
#pragma unroll
  for (int ks = 0; ks < 8; ++ks) {
    const int k0 = ks * 32;
    bf16x8 af[4], bfr[4];
#pragma unroll
    for (int nt = 0; nt < 4; ++nt)
      af[nt] = *(const bf16x8*)&Xt[(arow + nt * 16 + il) * CDIM + k0 + g * 8];
#pragma unroll
    for (int ct = 0; ct < 4; ++ct)
      bfr[ct] = *(const bf16x8*)&Wb[(size_t)(ccol + ct * 16 + il) * CDIM + k0 + g * 8];
#pragma unroll
    for (int nt = 0; nt < 4; ++nt)
#pragma unroll
      for (int ct = 0; ct < 4; ++ct)
        acc[nt][ct] = __builtin_amdgcn_mfma_f32_16x16x32_bf16(af[nt], bfr[ct], acc[nt][ct], 0, 0, 0);
  }
#pragma unroll
  for (int ct = 0; ct < 4; ++ct) {
    const int c = ccol + ct * 16 + il;
    const float bs = bias[c];
    float s = 0.f, ss = 0.f;
#pragma unroll
    for (int nt = 0; nt < 4; ++nt) {
      const int n = n0 + wn * 64 + nt * 16 + g * 4;
      float y0 = acc[nt][ct][0] + bs, y1 = acc[nt][ct][1] + bs;
      float y2 = acc[nt][ct][2] + bs, y3 = acc[nt][ct][3] + bs;
      *(uint2*)&OUT[((size_t)(b * CDIM + c)) * NDIM + n] =
          make_uint2(cvt_pk(y0, y1), cvt_pk(y2, y3));
      if (STATS) {
        s += y0 + y1 + y2 + y3;
        ss += y0 * y0 + y1 * y1 + y2 * y2 + y3 * y3;
      }
    }
    if (STATS) {
      s += __shfl_xor(s, 16, 64);   s += __shfl_xor(s, 32, 64);
      ss += __shfl_xor(ss, 16, 64); ss += __shfl_xor(ss, 32, 64);
      if (l < 16) { atomicAdd(&bnsum[c], s); atomicAdd(&bnss[c], ss); }
    }
  }
}

// ---------------------------------------------------------------------------
// qv_gemm: [0,256) v-gemm (128x128 tiles); [256,512) q-gemm + sq2 fusion.
// ---------------------------------------------------------------------------
__global__ __launch_bounds__(256) void qv_gemm(const short* __restrict__ wqb,
                                               const short* __restrict__ wvb,
                                               const short* __restrict__ xT,
                                               const float* __restrict__ bv,
                                               short* __restrict__ qT,
                                               float* __restrict__ sq2,
                                               short* __restrict__ vbf) {
  const int fb = blockIdx.x, t = threadIdx.x;
  if (fb < 256) {
    const int b = fb >> 5, c0 = ((fb >> 4) & 1) * 128, n0 = (fb & 15) * 128;
    gemm128<false>(wvb, xT, bv, vbf, nullptr, nullptr, b, n0, c0, t);
  } else {
    const int f = fb - 256;
    const int b = f >> 5, n0 = (f & 31) * 64;
    const int w = t >> 6, l = t & 63, il = l & 15, g = l >> 4;
    const int nw = n0 + w * 16;
    f32x4 acc[4] = {};
#pragma unroll
    for (int ks = 0; ks < 8; ++ks) {
      const int k0 = ks * 32;
      bf16x8 bx = *(const bf16x8*)&xT[((size_t)b * NDIM + nw + il) * CDIM + k0 + g * 8];
#pragma unroll
      for (int ot = 0; ot < 4; ++ot) {
        bf16x8 aw = *(const bf16x8*)&wqb[(size_t)(ot * 16 + il) * CDIM + k0 + g * 8];
        acc[ot] = __builtin_amdgcn_mfma_f32_16x16x32_bf16(aw, bx, acc[ot], 0, 0, 0);
      }
    }
    float sqs = 0.f;
#pragma unroll
    for (int ot = 0; ot < 4; ++ot) {
      unsigned u0 = cvt_pk(acc[ot][0], acc[ot][1]);
      unsigned u1 = cvt_pk(acc[ot][2], acc[ot][3]);
      *(uint2*)&qT[((size_t)b * NDIM + nw + il) * C4DIM + ot * 16 + g * 4] = make_uint2(u0, u1);
      float f0 = bflo(u0), f1 = bfhi(u0), f2 = bflo(u1), f3 = bfhi(u1);
      sqs += f0 * f0 + f1 * f1 + f2 * f2 + f3 * f3;
    }
    sqs += __shfl_xor(sqs, 16, 64);
    sqs += __shfl_xor(sqs, 32, 64);
    if (l < 16) sq2[(size_t)b * NDIM + nw + l] = sqs * LOG2E_SQ;
  }
}

// ---------------------------------------------------------------------------
// MFMA L2 attention — EXACT r5-passing structure (KVBLK=32), c-QUARTER split
// for occupancy: grid 1024 (4 blocks/CU), block = (b, 64 i, 64 c), 4 waves =
// i-subs.  Per-output math bit-identical to the r5 kernel (same gram order,
// same staging formulas); only the c-range per block changed (128 -> 64) and
// s_setprio around the PV MFMA cluster (scheduler hint, T5).
// ---------------------------------------------------------------------------
__global__ __launch_bounds__(256) void attn_mfma(const short* __restrict__ qT,
                                                 const short* __restrict__ Vb16,
                                                 const float* __restrict__ sq2,
                                                 short* __restrict__ xrT) {
  __shared__ __align__(16) short vj[2][64 * 32];    // own c-quarter, 4 KB each
  __shared__ __align__(16) short qj[2][32 * 64];    // 4 KB each
  __shared__ __align__(16) short wlds[4][16][40];   // per-wave w tiles

  const int bid = blockIdx.x;
  const int swz = (bid & 7) * 128 + (bid >> 3);     // XCD-contiguous, bijective
  const int i0 = (swz & 31) * 64;
  const int cq = (swz >> 5) & 3;
  const int b  = swz >> 7;

  const int t = threadIdx.x;
  const int w = t >> 6, l = t & 63, il = l & 15, g = l >> 4;

  const short* qTb = qT + (size_t)b * NDIM * C4DIM;
  const short* Vbb = Vb16 + ((size_t)b * CDIM + cq * 64) * NDIM;
  const float* sqb = sq2 + (size_t)b * NDIM;

  const int iglob = i0 + w * 16 + il;
  const bf16x8 bq0 = *(const bf16x8*)&qTb[(size_t)iglob * C4DIM + g * 8];
  const bf16x8 bq1 = *(const bf16x8*)&qTb[(size_t)iglob * C4DIM + 32 + g * 8];
  const float sqi = sqb[iglob];

  // staging maps (r5 formulas): V one row/thread now (64 rows), q unchanged
  const int vcb = t >> 2, vs = t & 3;
  const int vd = vcb * 32 + ((vs ^ ((vcb >> 1) & 3)) << 3);
  const int qrow = t >> 3, qslot = t & 7;
  const int qd = qrow * 64 + ((qslot ^ (qrow & 7)) << 3);

  f32x4 acc[4];
#pragma unroll
  for (int k = 0; k < 4; ++k) acc[k] = {0.f, 0.f, 0.f, 0.f};
  float sumw = 0.f;

  f32x4 sqc0, sqc1;
  { // prologue: stage step 0
    bf16x8 vr0 = *(const bf16x8*)&Vbb[(size_t)vcb * NDIM + vs * 8];
    *(bf16x8*)&vj[0][vd] = vr0;
    bf16x8 qr = *(const bf16x8*)&qTb[(size_t)qrow * C4DIM + qslot * 8];
    *(bf16x8*)&qj[0][qd] = qr;
    sqc0 = *(const f32x4*)&sqb[g * 4];
    sqc1 = *(const f32x4*)&sqb[16 + g * 4];
  }
  __syncthreads();

  const int NT = NDIM / 32;
  for (int jt = 0; jt < NT; ++jt) {
    const int p = jt & 1;
    const bool hn = (jt + 1 < NT);
    const int j0n = jt * 32 + 32;

    // ---- issue next-tile global loads (latency hides under compute) ----
    bf16x8 vr0 = {}, qr = {};
    f32x4 sqn0 = {}, sqn1 = {};
    if (hn) {
      vr0 = *(const bf16x8*)&Vbb[(size_t)vcb * NDIM + j0n + vs * 8];
      qr  = *(const bf16x8*)&qTb[(size_t)(j0n + qrow) * C4DIM + qslot * 8];
      sqn0 = *(const f32x4*)&sqb[j0n + g * 4];
      sqn1 = *(const f32x4*)&sqb[j0n + 16 + g * 4];
    }

    const short* qbuf = &qj[p][0];
    const short* vbuf = &vj[p][0];

    // ---- gram both halves: w[j = h*16 + g*4 + r][i = il] ----
#pragma unroll
    for (int h = 0; h < 2; ++h) {
      const int row = h * 16 + il;
      bf16x8 aJ0 = *(const bf16x8*)&qbuf[row * 64 + ((g ^ (il & 7)) << 3)];
      bf16x8 aJ1 = *(const bf16x8*)&qbuf[row * 64 + (((4 + g) ^ (il & 7)) << 3)];
      f32x4 s = {0.f, 0.f, 0.f, 0.f};
      s = __builtin_amdgcn_mfma_f32_16x16x32_bf16(aJ0, bq0, s, 0, 0, 0);
      s = __builtin_amdgcn_mfma_f32_16x16x32_bf16(aJ1, bq1, s, 0, 0, 0);
      const f32x4 sqh = h ? sqc1 : sqc0;
      float wv[4];
#pragma unroll
      for (int r = 0; r < 4; ++r) {
        float e = fmaxf(fmaf(NEG_2LOG2E_SQ, s[r], sqi + sqh[r]), 0.f);
        wv[r] = __builtin_amdgcn_exp2f(-__builtin_amdgcn_sqrtf(e));
        sumw += wv[r];
      }
      *(uint2*)&wlds[w][il][h * 16 + g * 4] =
          make_uint2(cvt_pk(wv[0], wv[1]), cvt_pk(wv[2], wv[3]));
    }

    // ---- intra-wave exchange (no barrier; compiler inserts lgkmcnt) ----
    const bf16x8 bw = *(const bf16x8*)&wlds[w][il][g * 8];

    // ---- PV: 4 c-tiles (this block's c-quarter) ----
    __builtin_amdgcn_s_setprio(1);
#pragma unroll
    for (int ctl = 0; ctl < 4; ++ctl) {
      const int lr = ctl * 16 + il;
      bf16x8 aV = *(const bf16x8*)&vbuf[lr * 32 + ((g ^ ((il >> 1) & 3)) << 3)];
      acc[ctl] = __builtin_amdgcn_mfma_f32_16x16x32_bf16(aV, bw, acc[ctl], 0, 0, 0);
    }
    __builtin_amdgcn_s_setprio(0);

    // ---- stage next tile into the other buffer ----
    if (hn) {
      *(bf16x8*)&vj[p ^ 1][vd] = vr0;
      *(bf16x8*)&qj[p ^ 1][qd] = qr;
      sqc0 = sqn0; sqc1 = sqn1;
    }
    __syncthreads();
  }

  // ---- normalize + bf16 transposed write ----
  sumw += __shfl_xor(sumw, 16, 64);
  sumw += __shfl_xor(sumw, 32, 64);
  const float inv = 1.f / sumw;
#pragma unroll
  for (int ctl = 0; ctl < 4; ++ctl) {
    float y0 = acc[ctl][0] * inv, y1 = acc[ctl][1] * inv;
    float y2 = acc[ctl][2] * inv, y3 = acc[ctl][3] * inv;
    *(uint2*)&xrT[((size_t)b * NDIM + iglob) * CDIM + cq * 64 + ctl * 16 + g * 4] =
        make_uint2(cvt_pk(y0, y1), cvt_pk(y2, y3));
  }
}

// ---------------------------------------------------------------------------
// t-gemm: t = wt*x_r + bt (bf16 out) + fused BN partial sums.
// ---------------------------------------------------------------------------
__global__ __launch_bounds__(256) void t_gemm(const short* __restrict__ wtb,
                                              const short* __restrict__ xrT,
                                              const float* __restrict__ bt,
                                              short* __restrict__ tbf,
                                              float* __restrict__ bnsum,
                                              float* __restrict__ bnss) {
  gemm128<true>(wtb, xrT, bt, tbf, bnsum, bnss,
                blockIdx.z, blockIdx.x * 128, blockIdx.y * 128, threadIdx.x);
}

// ---------------------------------------------------------------------------
// final: BN finalize (inline from sums) + out = x + relu(bn(t)), x fp32
// ---------------------------------------------------------------------------
__global__ __launch_bounds__(256) void final_kernel(const float* __restrict__ x,
                                                    const short* __restrict__ tbf,
                                                    const float* __restrict__ bnsum,
                                                    const float* __restrict__ bnss,
                                                    const float* __restrict__ gamma,
                                                    const float* __restrict__ beta,
                                                    float* __restrict__ out) {
  const size_t idx = ((size_t)blockIdx.x * 256 + threadIdx.x) << 2;
  const int c = (int)((idx >> 11) & 255);
  const float cnt = (float)(BDIM * NDIM);
  const float mean = bnsum[c] / cnt;
  const float var = fmaxf(bnss[c] / cnt - mean * mean, 0.f);
  const float sc = gamma[c] * rsqrtf(var + 1e-5f);
  const float sh = beta[c] - mean * sc;
  float4 xv = *(const float4*)&x[idx];
  uint2 tu = *(const uint2*)&tbf[idx];
  const float t0 = bflo(tu.x), t1 = bfhi(tu.x), t2 = bflo(tu.y), t3 = bfhi(tu.y);
  float4 r;
  r.x = xv.x + fmaxf(t0 * sc + sh, 0.f);
  r.y = xv.y + fmaxf(t1 * sc + sh, 0.f);
  r.z = xv.z + fmaxf(t2 * sc + sh, 0.f);
  r.w = xv.w + fmaxf(t3 * sc + sh, 0.f);
  *(float4*)&out[idx] = r;
}

extern "C" void kernel_launch(void* const* d_in, const int* in_sizes, int n_in,
                              void* d_out, int out_size, void* d_ws, size_t ws_size,
                              hipStream_t stream) {
  const float* x     = (const float*)d_in[0];
  const float* wq    = (const float*)d_in[1];
  const float* wv    = (const float*)d_in[2];
  const float* bv    = (const float*)d_in[3];
  const float* wt    = (const float*)d_in[4];
  const float* bt    = (const float*)d_in[5];
  const float* gamma = (const float*)d_in[6];
  const float* beta  = (const float*)d_in[7];
  float* out = (float*)d_out;
  char* ws = (char*)d_ws;

  short* xbT   = (short*)(ws);                       // [B][N][C] bf16  8 MB
  short* wqb   = (short*)(ws + ((size_t)9  << 20));  // 32 KB
  short* wvb   = (short*)(ws + ((size_t)9  << 20) + (256 << 10));
  short* wtb   = (short*)(ws + ((size_t)9  << 20) + (512 << 10));
  short* qT    = (short*)(ws + ((size_t)10 << 20));  // [B][N][64] bf16 2 MB
  float* sq2   = (float*)(ws + ((size_t)12 << 20));  // [B][N] f32
  short* vbf   = (short*)(ws + ((size_t)13 << 20));  // [B][C][N] bf16 8 MB
  short* xrT   = (short*)(ws + ((size_t)22 << 20));  // [B][N][C] bf16 8 MB
  short* tbf   = vbf;                                // reuse (v dead after attn)
  float* bnsum = (float*)(ws + ((size_t)31 << 20));  // 256 + 256
  float* bnss  = bnsum + 256;

  prep_kernel<<<dim3(1169), 256, 0, stream>>>(x, wq, wv, wt, xbT, wqb, wvb, wtb, bnsum);
  qv_gemm<<<dim3(512), 256, 0, stream>>>(wqb, wvb, xbT, bv, qT, sq2, vbf);
  attn_mfma<<<dim3(1024), 256, 0, stream>>>(qT, vbf, sq2, xrT);
  t_gemm<<<dim3(16, 2, 8), 256, 0, stream>>>(wtb, xrT, bt, tbf, bnsum, bnss);
  final_kernel<<<dim3(4096), 256, 0, stream>>>(x, tbf, bnsum, bnss, gamma, beta, out);
}

// Round 11
// 114.258 us; speedup vs baseline: 1.0695x; 1.0695x over previous
//
#include <hip/hip_runtime.h>
#include <math.h>

#define BDIM 8
#define CDIM 256
#define C4DIM 64
#define NDIM 2048
#define LOG2E_SQ 2.0813689810056077f
#define NEG_2LOG2E_SQ -4.1627379620112154f

typedef short bf16x8 __attribute__((ext_vector_type(8)));
typedef float f32x4 __attribute__((ext_vector_type(4)));

__device__ inline unsigned cvt_pk(float lo, float hi) {
  unsigned r;
  asm("v_cvt_pk_bf16_f32 %0, %1, %2" : "=v"(r) : "v"(lo), "v"(hi));
  return r;
}
__device__ inline float bflo(unsigned u) {
  u <<= 16; float f; __builtin_memcpy(&f, &u, 4); return f;
}
__device__ inline float bfhi(unsigned u) {
  u &= 0xffff0000u; float f; __builtin_memcpy(&f, &u, 4); return f;
}

// ---------------------------------------------------------------------------
// prep: [0,1024) castT x->xT bf16; [1024,1168) cast weights; 1168 zero bn sums
// ---------------------------------------------------------------------------
__global__ __launch_bounds__(256) void prep_kernel(const float* __restrict__ x,
                                                   const float* __restrict__ wq,
                                                   const float* __restrict__ wv,
                                                   const float* __restrict__ wt,
                                                   short* __restrict__ xT,
                                                   short* __restrict__ wqb,
                                                   short* __restrict__ wvb,
                                                   short* __restrict__ wtb,
                                                   float* __restrict__ bnsum) {
  __shared__ float tile[64][65];
  const int fb = blockIdx.x, t = threadIdx.x;
  if (fb < 1024) {
    const int b = fb >> 7, c0 = ((fb >> 5) & 3) * 64, n0 = (fb & 31) * 64;
    const int cl = t >> 2, ng = (t & 3) * 16;
#pragma unroll
    for (int kk = 0; kk < 4; ++kk) {
      float4 v = *(const float4*)&x[((size_t)(b * CDIM + c0 + cl)) * NDIM + n0 + ng + kk * 4];
      tile[cl][ng + kk * 4 + 0] = v.x; tile[cl][ng + kk * 4 + 1] = v.y;
      tile[cl][ng + kk * 4 + 2] = v.z; tile[cl][ng + kk * 4 + 3] = v.w;
    }
    __syncthreads();
    const int nl = t >> 2, cg = (t & 3) * 16;
    unsigned u[8];
#pragma unroll
    for (int e = 0; e < 8; ++e)
      u[e] = cvt_pk(tile[cg + 2 * e][nl], tile[cg + 2 * e + 1][nl]);
    short* dst = &xT[((size_t)b * NDIM + n0 + nl) * CDIM + c0 + cg];
    *(uint4*)&dst[0] = make_uint4(u[0], u[1], u[2], u[3]);
    *(uint4*)&dst[8] = make_uint4(u[4], u[5], u[6], u[7]);
  } else if (fb < 1168) {
    const int idx = ((fb - 1024) * 256 + t) * 4;
    const float* src; short* dst; int off;
    if (idx < 16384)      { src = wq; dst = wqb; off = idx; }
    else if (idx < 81920) { src = wv; dst = wvb; off = idx - 16384; }
    else                  { src = wt; dst = wtb; off = idx - 81920; }
    float4 v = *(const float4*)&src[off];
    *(uint2*)&dst[off] = make_uint2(cvt_pk(v.x, v.y), cvt_pk(v.z, v.w));
  } else {
    bnsum[t] = 0.f; bnsum[256 + t] = 0.f;
  }
}

// ---------------------------------------------------------------------------
// 128x128 MFMA GEMM body: OUT[b][c][n] (bf16) = W * X[b] + bias.
// STATS: fused BN partial sums via per-channel atomics.
// ---------------------------------------------------------------------------
template<bool STATS>
__device__ __forceinline__ void gemm128(const short* __restrict__ Wb,
                                        const short* __restrict__ Xt,
                                        const float* __restrict__ bias,
                                        short* __restrict__ OUT,
                                        float* __restrict__ bnsum,
                                        float* __restrict__ bnss,
                                        int b, int n0, int c0, int t) {
  const int w = t >> 6, l = t & 63, il = l & 15, g = l >> 4;
  const int wn = w & 1, wc = w >> 1;
  const size_t arow = (size_t)b * NDIM + n0 + wn * 64;
  const int ccol = c0 + wc * 64;
  f32x4 acc[4][4] = {};
#pragma unroll
  for (int ks = 0; ks < 8; ++ks) {
    const int k0 = ks * 32;
    bf16x8 af[4], bfr[4];
#pragma unroll
    for (int nt = 0; nt < 4; ++nt)
      af[nt] = *(const bf16x8*)&Xt[(arow + nt * 16 + il) * CDIM + k0 + g * 8];
#pragma unroll
    for (int ct = 0; ct < 4; ++ct)
      bfr[ct] = *(const bf16x8*)&Wb[(size_t)(ccol + ct * 16 + il) * CDIM + k0 + g * 8];
#pragma unroll
    for (int nt = 0; nt < 4; ++nt)
#pragma unroll
      for (int ct = 0; ct < 4; ++ct)
        acc[nt][ct] = __builtin_amdgcn_mfma_f32_16x16x32_bf16(af[nt], bfr[ct], acc[nt][ct], 0, 0, 0);
  }
#pragma unroll
  for (int ct = 0; ct < 4; ++ct) {
    const int c = ccol + ct * 16 + il;
    const float bs = bias[c];
    float s = 0.f, ss = 0.f;
#pragma unroll
    for (int nt = 0; nt < 4; ++nt) {
      const int n = n0 + wn * 64 + nt * 16 + g * 4;
      float y0 = acc[nt][ct][0] + bs, y1 = acc[nt][ct][1] + bs;
      float y2 = acc[nt][ct][2] + bs, y3 = acc[nt][ct][3] + bs;
      *(uint2*)&OUT[((size_t)(b * CDIM + c)) * NDIM + n] =
          make_uint2(cvt_pk(y0, y1), cvt_pk(y2, y3));
      if (STATS) {
        s += y0 + y1 + y2 + y3;
        ss += y0 * y0 + y1 * y1 + y2 * y2 + y3 * y3;
      }
    }
    if (STATS) {
      s += __shfl_xor(s, 16, 64);   s += __shfl_xor(s, 32, 64);
      ss += __shfl_xor(ss, 16, 64); ss += __shfl_xor(ss, 32, 64);
      if (l < 16) { atomicAdd(&bnsum[c], s); atomicAdd(&bnss[c], ss); }
    }
  }
}

// ---------------------------------------------------------------------------
// qv_gemm: [0,256) v-gemm (128x128 tiles); [256,512) q-gemm + sq2 fusion.
// ---------------------------------------------------------------------------
__global__ __launch_bounds__(256) void qv_gemm(const short* __restrict__ wqb,
                                               const short* __restrict__ wvb,
                                               const short* __restrict__ xT,
                                               const float* __restrict__ bv,
                                               short* __restrict__ qT,
                                               float* __restrict__ sq2,
                                               short* __restrict__ vbf) {
  const int fb = blockIdx.x, t = threadIdx.x;
  if (fb < 256) {
    const int b = fb >> 5, c0 = ((fb >> 4) & 1) * 128, n0 = (fb & 15) * 128;
    gemm128<false>(wvb, xT, bv, vbf, nullptr, nullptr, b, n0, c0, t);
  } else {
    const int f = fb - 256;
    const int b = f >> 5, n0 = (f & 31) * 64;
    const int w = t >> 6, l = t & 63, il = l & 15, g = l >> 4;
    const int nw = n0 + w * 16;
    f32x4 acc[4] = {};
#pragma unroll
    for (int ks = 0; ks < 8; ++ks) {
      const int k0 = ks * 32;
      bf16x8 bx = *(const bf16x8*)&xT[((size_t)b * NDIM + nw + il) * CDIM + k0 + g * 8];
#pragma unroll
      for (int ot = 0; ot < 4; ++ot) {
        bf16x8 aw = *(const bf16x8*)&wqb[(size_t)(ot * 16 + il) * CDIM + k0 + g * 8];
        acc[ot] = __builtin_amdgcn_mfma_f32_16x16x32_bf16(aw, bx, acc[ot], 0, 0, 0);
      }
    }
    float sqs = 0.f;
#pragma unroll
    for (int ot = 0; ot < 4; ++ot) {
      unsigned u0 = cvt_pk(acc[ot][0], acc[ot][1]);
      unsigned u1 = cvt_pk(acc[ot][2], acc[ot][3]);
      *(uint2*)&qT[((size_t)b * NDIM + nw + il) * C4DIM + ot * 16 + g * 4] = make_uint2(u0, u1);
      float f0 = bflo(u0), f1 = bfhi(u0), f2 = bflo(u1), f3 = bfhi(u1);
      sqs += f0 * f0 + f1 * f1 + f2 * f2 + f3 * f3;
    }
    sqs += __shfl_xor(sqs, 16, 64);
    sqs += __shfl_xor(sqs, 32, 64);
    if (l < 16) sq2[(size_t)b * NDIM + nw + l] = sqs * LOG2E_SQ;
  }
}

// ---------------------------------------------------------------------------
// MFMA L2 attention — r5-passing math repackaged into 2-wave blocks.
// Grid 1024 x 128 thr (4 blocks/CU = 4 independent barrier groups; same
// 8 waves/CU and same total work as the r5 kernel).  Block = (b, 32 i,
// c-half 128); wave w = i-sub of 16.  Per-wave per-step work is IDENTICAL
// to r5 (gram both halves dup x2 across chalf blocks, softmax 8 vals,
// PV 8 c-tiles); staging rows are re-distributed over 128 threads with the
// same swizzle keys (invariant under +32k / +16 row shifts).
// ---------------------------------------------------------------------------
__global__ __launch_bounds__(128) void attn_mfma(const short* __restrict__ qT,
                                                 const short* __restrict__ Vb16,
                                                 const float* __restrict__ sq2,
                                                 short* __restrict__ xrT) {
  __shared__ __align__(16) short vj[2][128 * 32];   // c-half V, 8 KB each
  __shared__ __align__(16) short qj[2][32 * 64];    // 4 KB each
  __shared__ __align__(16) short wlds[2][16][40];   // per-wave w tiles

  const int bid = blockIdx.x;
  const int swz = (bid & 7) * 128 + (bid >> 3);     // XCD-contiguous, bijective
  const int i0    = (swz & 63) * 32;
  const int chalf = (swz >> 6) & 1;
  const int b     = swz >> 7;

  const int t = threadIdx.x;
  const int w = t >> 6, l = t & 63, il = l & 15, g = l >> 4;

  const short* qTb = qT + (size_t)b * NDIM * C4DIM;
  const short* Vbb = Vb16 + ((size_t)b * CDIM + chalf * 128) * NDIM;
  const float* sqb = sq2 + (size_t)b * NDIM;

  const int iglob = i0 + w * 16 + il;
  const bf16x8 bq0 = *(const bf16x8*)&qTb[(size_t)iglob * C4DIM + g * 8];
  const bf16x8 bq1 = *(const bf16x8*)&qTb[(size_t)iglob * C4DIM + 32 + g * 8];
  const float sqi = sqb[iglob];

  // staging maps (r5 swizzle keys, rows spread over 128 threads):
  // V rows vcb+32k (k=0..3), q rows qrow, qrow+16
  const int vcb = t >> 2, vs = t & 3;
  const int vd = vcb * 32 + ((vs ^ ((vcb >> 1) & 3)) << 3);
  const int qrow = t >> 3, qslot = t & 7;
  const int qd = qrow * 64 + ((qslot ^ (qrow & 7)) << 3);

  f32x4 acc[8];
#pragma unroll
  for (int k = 0; k < 8; ++k) acc[k] = {0.f, 0.f, 0.f, 0.f};
  float sumw = 0.f;

  f32x4 sqc0, sqc1;
  { // prologue: stage step 0
#pragma unroll
    for (int k = 0; k < 4; ++k) {
      bf16x8 vr = *(const bf16x8*)&Vbb[(size_t)(vcb + 32 * k) * NDIM + vs * 8];
      *(bf16x8*)&vj[0][vd + k * 1024] = vr;
    }
    bf16x8 qa = *(const bf16x8*)&qTb[(size_t)qrow * C4DIM + qslot * 8];
    bf16x8 qb = *(const bf16x8*)&qTb[(size_t)(qrow + 16) * C4DIM + qslot * 8];
    *(bf16x8*)&qj[0][qd] = qa;
    *(bf16x8*)&qj[0][qd + 1024] = qb;
    sqc0 = *(const f32x4*)&sqb[g * 4];
    sqc1 = *(const f32x4*)&sqb[16 + g * 4];
  }
  __syncthreads();

  const int NT = NDIM / 32;
  for (int jt = 0; jt < NT; ++jt) {
    const int p = jt & 1;
    const bool hn = (jt + 1 < NT);
    const int j0n = jt * 32 + 32;

    // ---- issue next-tile global loads (latency hides under compute) ----
    bf16x8 nv[4] = {}, nqa = {}, nqb = {};
    f32x4 sqn0 = {}, sqn1 = {};
    if (hn) {
#pragma unroll
      for (int k = 0; k < 4; ++k)
        nv[k] = *(const bf16x8*)&Vbb[(size_t)(vcb + 32 * k) * NDIM + j0n + vs * 8];
      nqa = *(const bf16x8*)&qTb[(size_t)(j0n + qrow) * C4DIM + qslot * 8];
      nqb = *(const bf16x8*)&qTb[(size_t)(j0n + qrow + 16) * C4DIM + qslot * 8];
      sqn0 = *(const f32x4*)&sqb[j0n + g * 4];
      sqn1 = *(const f32x4*)&sqb[j0n + 16 + g * 4];
    }

    const short* qbuf = &qj[p][0];
    const short* vbuf = &vj[p][0];

    // ---- gram both halves: w[j = h*16 + g*4 + r][i = il] ----
#pragma unroll
    for (int h = 0; h < 2; ++h) {
      const int row = h * 16 + il;
      bf16x8 aJ0 = *(const bf16x8*)&qbuf[row * 64 + ((g ^ (il & 7)) << 3)];
      bf16x8 aJ1 = *(const bf16x8*)&qbuf[row * 64 + (((4 + g) ^ (il & 7)) << 3)];
      f32x4 s = {0.f, 0.f, 0.f, 0.f};
      s = __builtin_amdgcn_mfma_f32_16x16x32_bf16(aJ0, bq0, s, 0, 0, 0);
      s = __builtin_amdgcn_mfma_f32_16x16x32_bf16(aJ1, bq1, s, 0, 0, 0);
      const f32x4 sqh = h ? sqc1 : sqc0;
      float wv[4];
#pragma unroll
      for (int r = 0; r < 4; ++r) {
        float e = fmaxf(fmaf(NEG_2LOG2E_SQ, s[r], sqi + sqh[r]), 0.f);
        wv[r] = __builtin_amdgcn_exp2f(-__builtin_amdgcn_sqrtf(e));
        sumw += wv[r];
      }
      *(uint2*)&wlds[w][il][h * 16 + g * 4] =
          make_uint2(cvt_pk(wv[0], wv[1]), cvt_pk(wv[2], wv[3]));
    }

    // ---- intra-wave exchange (no barrier; compiler inserts lgkmcnt) ----
    const bf16x8 bw = *(const bf16x8*)&wlds[w][il][g * 8];

    // ---- PV: 8 c-tiles (this block's c-half) ----
    __builtin_amdgcn_s_setprio(1);
#pragma unroll
    for (int ctl = 0; ctl < 8; ++ctl) {
      const int lr = ctl * 16 + il;
      bf16x8 aV = *(const bf16x8*)&vbuf[lr * 32 + ((g ^ ((il >> 1) & 3)) << 3)];
      acc[ctl] = __builtin_amdgcn_mfma_f32_16x16x32_bf16(aV, bw, acc[ctl], 0, 0, 0);
    }
    __builtin_amdgcn_s_setprio(0);

    // ---- stage next tile into the other buffer ----
    if (hn) {
#pragma unroll
      for (int k = 0; k < 4; ++k) *(bf16x8*)&vj[p ^ 1][vd + k * 1024] = nv[k];
      *(bf16x8*)&qj[p ^ 1][qd] = nqa;
      *(bf16x8*)&qj[p ^ 1][qd + 1024] = nqb;
      sqc0 = sqn0; sqc1 = sqn1;
    }
    __syncthreads();
  }

  // ---- normalize + bf16 transposed write ----
  sumw += __shfl_xor(sumw, 16, 64);
  sumw += __shfl_xor(sumw, 32, 64);
  const float inv = 1.f / sumw;
#pragma unroll
  for (int ctl = 0; ctl < 8; ++ctl) {
    float y0 = acc[ctl][0] * inv, y1 = acc[ctl][1] * inv;
    float y2 = acc[ctl][2] * inv, y3 = acc[ctl][3] * inv;
    *(uint2*)&xrT[((size_t)b * NDIM + iglob) * CDIM + chalf * 128 + ctl * 16 + g * 4] =
        make_uint2(cvt_pk(y0, y1), cvt_pk(y2, y3));
  }
}

// ---------------------------------------------------------------------------
// t-gemm: t = wt*x_r + bt (bf16 out) + fused BN partial sums.
// ---------------------------------------------------------------------------
__global__ __launch_bounds__(256) void t_gemm(const short* __restrict__ wtb,
                                              const short* __restrict__ xrT,
                                              const float* __restrict__ bt,
                                              short* __restrict__ tbf,
                                              float* __restrict__ bnsum,
                                              float* __restrict__ bnss) {
  gemm128<true>(wtb, xrT, bt, tbf, bnsum, bnss,
                blockIdx.z, blockIdx.x * 128, blockIdx.y * 128, threadIdx.x);
}

// ---------------------------------------------------------------------------
// final: BN finalize (inline from sums) + out = x + relu(bn(t)), x fp32
// ---------------------------------------------------------------------------
__global__ __launch_bounds__(256) void final_kernel(const float* __restrict__ x,
                                                    const short* __restrict__ tbf,
                                                    const float* __restrict__ bnsum,
                                                    const float* __restrict__ bnss,
                                                    const float* __restrict__ gamma,
                                                    const float* __restrict__ beta,
                                                    float* __restrict__ out) {
  const size_t idx = ((size_t)blockIdx.x * 256 + threadIdx.x) << 2;
  const int c = (int)((idx >> 11) & 255);
  const float cnt = (float)(BDIM * NDIM);
  const float mean = bnsum[c] / cnt;
  const float var = fmaxf(bnss[c] / cnt - mean * mean, 0.f);
  const float sc = gamma[c] * rsqrtf(var + 1e-5f);
  const float sh = beta[c] - mean * sc;
  float4 xv = *(const float4*)&x[idx];
  uint2 tu = *(const uint2*)&tbf[idx];
  const float t0 = bflo(tu.x), t1 = bfhi(tu.x), t2 = bflo(tu.y), t3 = bfhi(tu.y);
  float4 r;
  r.x = xv.x + fmaxf(t0 * sc + sh, 0.f);
  r.y = xv.y + fmaxf(t1 * sc + sh, 0.f);
  r.z = xv.z + fmaxf(t2 * sc + sh, 0.f);
  r.w = xv.w + fmaxf(t3 * sc + sh, 0.f);
  *(float4*)&out[idx] = r;
}

extern "C" void kernel_launch(void* const* d_in, const int* in_sizes, int n_in,
                              void* d_out, int out_size, void* d_ws, size_t ws_size,
                              hipStream_t stream) {
  const float* x     = (const float*)d_in[0];
  const float* wq    = (const float*)d_in[1];
  const float* wv    = (const float*)d_in[2];
  const float* bv    = (const float*)d_in[3];
  const float* wt    = (const float*)d_in[4];
  const float* bt    = (const float*)d_in[5];
  const float* gamma = (const float*)d_in[6];
  const float* beta  = (const float*)d_in[7];
  float* out = (float*)d_out;
  char* ws = (char*)d_ws;

  short* xbT   = (short*)(ws);                       // [B][N][C] bf16  8 MB
  short* wqb   = (short*)(ws + ((size_t)9  << 20));  // 32 KB
  short* wvb   = (short*)(ws + ((size_t)9  << 20) + (256 << 10));
  short* wtb   = (short*)(ws + ((size_t)9  << 20) + (512 << 10));
  short* qT    = (short*)(ws + ((size_t)10 << 20));  // [B][N][64] bf16 2 MB
  float* sq2   = (float*)(ws + ((size_t)12 << 20));  // [B][N] f32
  short* vbf   = (short*)(ws + ((size_t)13 << 20));  // [B][C][N] bf16 8 MB
  short* xrT   = (short*)(ws + ((size_t)22 << 20));  // [B][N][C] bf16 8 MB
  short* tbf   = vbf;                                // reuse (v dead after attn)
  float* bnsum = (float*)(ws + ((size_t)31 << 20));  // 256 + 256
  float* bnss  = bnsum + 256;

  prep_kernel<<<dim3(1169), 256, 0, stream>>>(x, wq, wv, wt, xbT, wqb, wvb, wtb, bnsum);
  qv_gemm<<<dim3(512), 256, 0, stream>>>(wqb, wvb, xbT, bv, qT, sq2, vbf);
  attn_mfma<<<dim3(1024), 128, 0, stream>>>(qT, vbf, sq2, xrT);
  t_gemm<<<dim3(16, 2, 8), 256, 0, stream>>>(wtb, xrT, bt, tbf, bnsum, bnss);
  final_kernel<<<dim3(4096), 256, 0, stream>>>(x, tbf, bnsum, bnss, gamma, beta, out);
}

// Round 12
// 102.550 us; speedup vs baseline: 1.1916x; 1.1142x over previous
//
#include <hip/hip_runtime.h>
#include <math.h>

#define BDIM 8
#define CDIM 256
#define C4DIM 64
#define NDIM 2048
#define LOG2E_SQ 2.0813689810056077f
#define NEG_2LOG2E_SQ -4.1627379620112154f

typedef short bf16x8 __attribute__((ext_vector_type(8)));
typedef float f32x4 __attribute__((ext_vector_type(4)));

__device__ inline unsigned cvt_pk(float lo, float hi) {
  unsigned r;
  asm("v_cvt_pk_bf16_f32 %0, %1, %2" : "=v"(r) : "v"(lo), "v"(hi));
  return r;
}
__device__ inline float bflo(unsigned u) {
  u <<= 16; float f; __builtin_memcpy(&f, &u, 4); return f;
}
__device__ inline float bfhi(unsigned u) {
  u &= 0xffff0000u; float f; __builtin_memcpy(&f, &u, 4); return f;
}

// ---------------------------------------------------------------------------
// prep: [0,1024) castT x->xT bf16; [1024,1168) cast weights; 1168 zero bn sums
// ---------------------------------------------------------------------------
__global__ __launch_bounds__(256) void prep_kernel(const float* __restrict__ x,
                                                   const float* __restrict__ wq,
                                                   const float* __restrict__ wv,
                                                   const float* __restrict__ wt,
                                                   short* __restrict__ xT,
                                                   short* __restrict__ wqb,
                                                   short* __restrict__ wvb,
                                                   short* __restrict__ wtb,
                                                   float* __restrict__ bnsum) {
  __shared__ float tile[64][65];
  const int fb = blockIdx.x, t = threadIdx.x;
  if (fb < 1024) {
    const int b = fb >> 7, c0 = ((fb >> 5) & 3) * 64, n0 = (fb & 31) * 64;
    const int cl = t >> 2, ng = (t & 3) * 16;
#pragma unroll
    for (int kk = 0; kk < 4; ++kk) {
      float4 v = *(const float4*)&x[((size_t)(b * CDIM + c0 + cl)) * NDIM + n0 + ng + kk * 4];
      tile[cl][ng + kk * 4 + 0] = v.x; tile[cl][ng + kk * 4 + 1] = v.y;
      tile[cl][ng + kk * 4 + 2] = v.z; tile[cl][ng + kk * 4 + 3] = v.w;
    }
    __syncthreads();
    const int nl = t >> 2, cg = (t & 3) * 16;
    unsigned u[8];
#pragma unroll
    for (int e = 0; e < 8; ++e)
      u[e] = cvt_pk(tile[cg + 2 * e][nl], tile[cg + 2 * e + 1][nl]);
    short* dst = &xT[((size_t)b * NDIM + n0 + nl) * CDIM + c0 + cg];
    *(uint4*)&dst[0] = make_uint4(u[0], u[1], u[2], u[3]);
    *(uint4*)&dst[8] = make_uint4(u[4], u[5], u[6], u[7]);
  } else if (fb < 1168) {
    const int idx = ((fb - 1024) * 256 + t) * 4;
    const float* src; short* dst; int off;
    if (idx < 16384)      { src = wq; dst = wqb; off = idx; }
    else if (idx < 81920) { src = wv; dst = wvb; off = idx - 16384; }
    else                  { src = wt; dst = wtb; off = idx - 81920; }
    float4 v = *(const float4*)&src[off];
    *(uint2*)&dst[off] = make_uint2(cvt_pk(v.x, v.y), cvt_pk(v.z, v.w));
  } else {
    bnsum[t] = 0.f; bnsum[256 + t] = 0.f;
  }
}

// ---------------------------------------------------------------------------
// 128x128 MFMA GEMM body: OUT[b][c][n] (bf16) = W * X[b] + bias.
// STATS: fused BN partial sums via per-channel atomics.
// ---------------------------------------------------------------------------
template<bool STATS>
__device__ __forceinline__ void gemm128(const short* __restrict__ Wb,
                                        const short* __restrict__ Xt,
                                        const float* __restrict__ bias,
                                        short* __restrict__ OUT,
                                        float* __restrict__ bnsum,
                                        float* __restrict__ bnss,
                                        int b, int n0, int c0, int t) {
  const int w = t >> 6, l = t & 63, il = l & 15, g = l >> 4;
  const int wn = w & 1, wc = w >> 1;
  const size_t arow = (size_t)b * NDIM + n0 + wn * 64;
  const int ccol = c0 + wc * 64;
  f32x4 acc[4][4] = {};
#pragma unroll
  for (int ks = 0; ks < 8; ++ks) {
    const int k0 = ks * 32;
    bf16x8 af[4], bfr[4];
#pragma unroll
    for (int nt = 0; nt < 4; ++nt)
      af[nt] = *(const bf16x8*)&Xt[(arow + nt * 16 + il) * CDIM + k0 + g * 8];
#pragma unroll
    for (int ct = 0; ct < 4; ++ct)
      bfr[ct] = *(const bf16x8*)&Wb[(size_t)(ccol + ct * 16 + il) * CDIM + k0 + g * 8];
#pragma unroll
    for (int nt = 0; nt < 4; ++nt)
#pragma unroll
      for (int ct = 0; ct < 4; ++ct)
        acc[nt][ct] = __builtin_amdgcn_mfma_f32_16x16x32_bf16(af[nt], bfr[ct], acc[nt][ct], 0, 0, 0);
  }
#pragma unroll
  for (int ct = 0; ct < 4; ++ct) {
    const int c = ccol + ct * 16 + il;
    const float bs = bias[c];
    float s = 0.f, ss = 0.f;
#pragma unroll
    for (int nt = 0; nt < 4; ++nt) {
      const int n = n0 + wn * 64 + nt * 16 + g * 4;
      float y0 = acc[nt][ct][0] + bs, y1 = acc[nt][ct][1] + bs;
      float y2 = acc[nt][ct][2] + bs, y3 = acc[nt][ct][3] + bs;
      *(uint2*)&OUT[((size_t)(b * CDIM + c)) * NDIM + n] =
          make_uint2(cvt_pk(y0, y1), cvt_pk(y2, y3));
      if (STATS) {
        s += y0 + y1 + y2 + y3;
        ss += y0 * y0 + y1 * y1 + y2 * y2 + y3 * y3;
      }
    }
    if (STATS) {
      s += __shfl_xor(s, 16, 64);   s += __shfl_xor(s, 32, 64);
      ss += __shfl_xor(ss, 16, 64); ss += __shfl_xor(ss, 32, 64);
      if (l < 16) { atomicAdd(&bnsum[c], s); atomicAdd(&bnss[c], ss); }
    }
  }
}

// ---------------------------------------------------------------------------
// qv_gemm: [0,256) v-gemm (128x128 tiles); [256,512) q-gemm + sq2 fusion.
// ---------------------------------------------------------------------------
__global__ __launch_bounds__(256) void qv_gemm(const short* __restrict__ wqb,
                                               const short* __restrict__ wvb,
                                               const short* __restrict__ xT,
                                               const float* __restrict__ bv,
                                               short* __restrict__ qT,
                                               float* __restrict__ sq2,
                                               short* __restrict__ vbf) {
  const int fb = blockIdx.x, t = threadIdx.x;
  if (fb < 256) {
    const int b = fb >> 5, c0 = ((fb >> 4) & 1) * 128, n0 = (fb & 15) * 128;
    gemm128<false>(wvb, xT, bv, vbf, nullptr, nullptr, b, n0, c0, t);
  } else {
    const int f = fb - 256;
    const int b = f >> 5, n0 = (f & 31) * 64;
    const int w = t >> 6, l = t & 63, il = l & 15, g = l >> 4;
    const int nw = n0 + w * 16;
    f32x4 acc[4] = {};
#pragma unroll
    for (int ks = 0; ks < 8; ++ks) {
      const int k0 = ks * 32;
      bf16x8 bx = *(const bf16x8*)&xT[((size_t)b * NDIM + nw + il) * CDIM + k0 + g * 8];
#pragma unroll
      for (int ot = 0; ot < 4; ++ot) {
        bf16x8 aw = *(const bf16x8*)&wqb[(size_t)(ot * 16 + il) * CDIM + k0 + g * 8];
        acc[ot] = __builtin_amdgcn_mfma_f32_16x16x32_bf16(aw, bx, acc[ot], 0, 0, 0);
      }
    }
    float sqs = 0.f;
#pragma unroll
    for (int ot = 0; ot < 4; ++ot) {
      unsigned u0 = cvt_pk(acc[ot][0], acc[ot][1]);
      unsigned u1 = cvt_pk(acc[ot][2], acc[ot][3]);
      *(uint2*)&qT[((size_t)b * NDIM + nw + il) * C4DIM + ot * 16 + g * 4] = make_uint2(u0, u1);
      float f0 = bflo(u0), f1 = bfhi(u0), f2 = bflo(u1), f3 = bfhi(u1);
      sqs += f0 * f0 + f1 * f1 + f2 * f2 + f3 * f3;
    }
    sqs += __shfl_xor(sqs, 16, 64);
    sqs += __shfl_xor(sqs, 32, 64);
    if (l < 16) sq2[(size_t)b * NDIM + nw + l] = sqs * LOG2E_SQ;
  }
}

// ---------------------------------------------------------------------------
// MFMA L2 attention — EXACT r5 topology (grid 512, 256 thr, block = b x 64 i
// x c-half 128, wave = i-sub, dup x2 gram) + r6's PROVEN 1-step PV lag:
// step jt: issue loads(V(jt), q(jt+1)) -> gram(jt) MFMA -> PV(jt-1) MFMA
// (reads LAST step's wlds/vj, independent of this step's softmax trans
// chain) -> softmax(jt) -> wlds[p] write -> stage writes -> ONE barrier.
// All buffers double-buffered; every WAR barrier-separated (r6 proof).
// Accumulation order over tiles unchanged -> bit-identical to r5 output.
// ---------------------------------------------------------------------------
__global__ __launch_bounds__(256) void attn_mfma(const short* __restrict__ qT,
                                                 const short* __restrict__ Vb16,
                                                 const float* __restrict__ sq2,
                                                 short* __restrict__ xrT) {
  __shared__ __align__(16) short vj[2][128 * 32];    // c-half V, 8 KB each
  __shared__ __align__(16) short qj[2][32 * 64];     // 4 KB each
  __shared__ __align__(16) short wlds[2][4][16][40]; // [dbuf][wave][i][j]

  const int bid = blockIdx.x;
  const int swz = (bid & 7) * 64 + (bid >> 3);       // XCD-contiguous
  const int i0    = (swz & 31) * 64;
  const int chalf = (swz >> 5) & 1;
  const int b     = swz >> 6;

  const int t = threadIdx.x;
  const int w = t >> 6, l = t & 63, il = l & 15, g = l >> 4;

  const short* qTb = qT + (size_t)b * NDIM * C4DIM;
  const short* Vbb = Vb16 + ((size_t)b * CDIM + chalf * 128) * NDIM;
  const float* sqb = sq2 + (size_t)b * NDIM;

  const int iglob = i0 + w * 16 + il;
  const bf16x8 bq0 = *(const bf16x8*)&qTb[(size_t)iglob * C4DIM + g * 8];
  const bf16x8 bq1 = *(const bf16x8*)&qTb[(size_t)iglob * C4DIM + 32 + g * 8];
  const float sqi = sqb[iglob];

  // staging maps (r5 formulas)
  const int vcb = t >> 2, vs = t & 3;
  const int vd0 = vcb * 32 + ((vs ^ ((vcb >> 1) & 3)) << 3);
  const int vd1 = vd0 + 64 * 32;
  const int qrow = t >> 3, qslot = t & 7;
  const int qd = qrow * 64 + ((qslot ^ (qrow & 7)) << 3);

  f32x4 acc[8];
#pragma unroll
  for (int k = 0; k < 8; ++k) acc[k] = {0.f, 0.f, 0.f, 0.f};
  float sumw = 0.f;

  f32x4 sqc0, sqc1;
  { // prologue: stage q(0), sq(0) only (V(0) staged during step 0)
    bf16x8 qr = *(const bf16x8*)&qTb[(size_t)qrow * C4DIM + qslot * 8];
    *(bf16x8*)&qj[0][qd] = qr;
    sqc0 = *(const f32x4*)&sqb[g * 4];
    sqc1 = *(const f32x4*)&sqb[16 + g * 4];
  }
  __syncthreads();

  const int NT = NDIM / 32;
  for (int jt = 0; jt <= NT; ++jt) {
    const int p = jt & 1;
    const bool dg = (jt < NT);        // gram this step
    const bool dp = (jt > 0);         // PV of previous tile
    const bool nq = (jt + 1 < NT);    // q/sq prefetch for next tile

    // ---- issue global loads: V(jt) and q/sq(jt+1) ----
    bf16x8 vr0 = {}, vr1 = {}, qr = {};
    f32x4 tn0 = {}, tn1 = {};
    if (dg) {
      const int j0 = jt * 32;
      vr0 = *(const bf16x8*)&Vbb[(size_t)vcb * NDIM + j0 + vs * 8];
      vr1 = *(const bf16x8*)&Vbb[(size_t)(vcb + 64) * NDIM + j0 + vs * 8];
    }
    if (nq) {
      const int j1 = (jt + 1) * 32;
      qr  = *(const bf16x8*)&qTb[(size_t)(j1 + qrow) * C4DIM + qslot * 8];
      tn0 = *(const f32x4*)&sqb[j1 + g * 4];
      tn1 = *(const f32x4*)&sqb[j1 + 16 + g * 4];
    }

    // ---- gram(jt): both halves, MFMA only (softmax deferred past PV) ----
    f32x4 s0 = {0.f, 0.f, 0.f, 0.f}, s1 = {0.f, 0.f, 0.f, 0.f};
    if (dg) {
      const short* qbuf = &qj[p][0];
      {
        const int row = il;
        bf16x8 aJ0 = *(const bf16x8*)&qbuf[row * 64 + ((g ^ (il & 7)) << 3)];
        bf16x8 aJ1 = *(const bf16x8*)&qbuf[row * 64 + (((4 + g) ^ (il & 7)) << 3)];
        s0 = __builtin_amdgcn_mfma_f32_16x16x32_bf16(aJ0, bq0, s0, 0, 0, 0);
        s0 = __builtin_amdgcn_mfma_f32_16x16x32_bf16(aJ1, bq1, s0, 0, 0, 0);
      }
      {
        const int row = 16 + il;
        bf16x8 aJ0 = *(const bf16x8*)&qbuf[row * 64 + ((g ^ (il & 7)) << 3)];
        bf16x8 aJ1 = *(const bf16x8*)&qbuf[row * 64 + (((4 + g) ^ (il & 7)) << 3)];
        s1 = __builtin_amdgcn_mfma_f32_16x16x32_bf16(aJ0, bq0, s1, 0, 0, 0);
        s1 = __builtin_amdgcn_mfma_f32_16x16x32_bf16(aJ1, bq1, s1, 0, 0, 0);
      }
    }

    // ---- PV(jt-1): last step's w + V, independent of this step's softmax --
    if (dp) {
      const int pp = p ^ 1;
      const short* vbuf = &vj[pp][0];
      const bf16x8 bw = *(const bf16x8*)&wlds[pp][w][il][g * 8];
      __builtin_amdgcn_s_setprio(1);
#pragma unroll
      for (int ctl = 0; ctl < 8; ++ctl) {
        const int lr = ctl * 16 + il;
        bf16x8 aV = *(const bf16x8*)&vbuf[lr * 32 + ((g ^ ((il >> 1) & 3)) << 3)];
        acc[ctl] = __builtin_amdgcn_mfma_f32_16x16x32_bf16(aV, bw, acc[ctl], 0, 0, 0);
      }
      __builtin_amdgcn_s_setprio(0);
    }

    // ---- softmax(jt) + wlds[p] write ----
    if (dg) {
      float wv0[4], wv1[4];
#pragma unroll
      for (int r = 0; r < 4; ++r) {
        float e0 = fmaxf(fmaf(NEG_2LOG2E_SQ, s0[r], sqi + sqc0[r]), 0.f);
        wv0[r] = __builtin_amdgcn_exp2f(-__builtin_amdgcn_sqrtf(e0));
        sumw += wv0[r];
        float e1 = fmaxf(fmaf(NEG_2LOG2E_SQ, s1[r], sqi + sqc1[r]), 0.f);
        wv1[r] = __builtin_amdgcn_exp2f(-__builtin_amdgcn_sqrtf(e1));
        sumw += wv1[r];
      }
      *(uint2*)&wlds[p][w][il][g * 4] =
          make_uint2(cvt_pk(wv0[0], wv0[1]), cvt_pk(wv0[2], wv0[3]));
      *(uint2*)&wlds[p][w][il][16 + g * 4] =
          make_uint2(cvt_pk(wv1[0], wv1[1]), cvt_pk(wv1[2], wv1[3]));
    }

    // ---- stage writes for V(jt) and q(jt+1) ----
    if (dg) {
      *(bf16x8*)&vj[p][vd0] = vr0;
      *(bf16x8*)&vj[p][vd1] = vr1;
    }
    if (nq) {
      *(bf16x8*)&qj[p ^ 1][qd] = qr;
      sqc0 = tn0; sqc1 = tn1;
    }
    __syncthreads();
  }

  // ---- normalize + bf16 transposed write ----
  sumw += __shfl_xor(sumw, 16, 64);
  sumw += __shfl_xor(sumw, 32, 64);
  const float inv = 1.f / sumw;
#pragma unroll
  for (int ctl = 0; ctl < 8; ++ctl) {
    float y0 = acc[ctl][0] * inv, y1 = acc[ctl][1] * inv;
    float y2 = acc[ctl][2] * inv, y3 = acc[ctl][3] * inv;
    *(uint2*)&xrT[((size_t)b * NDIM + iglob) * CDIM + chalf * 128 + ctl * 16 + g * 4] =
        make_uint2(cvt_pk(y0, y1), cvt_pk(y2, y3));
  }
}

// ---------------------------------------------------------------------------
// t-gemm: t = wt*x_r + bt (bf16 out) + fused BN partial sums.
// ---------------------------------------------------------------------------
__global__ __launch_bounds__(256) void t_gemm(const short* __restrict__ wtb,
                                              const short* __restrict__ xrT,
                                              const float* __restrict__ bt,
                                              short* __restrict__ tbf,
                                              float* __restrict__ bnsum,
                                              float* __restrict__ bnss) {
  gemm128<true>(wtb, xrT, bt, tbf, bnsum, bnss,
                blockIdx.z, blockIdx.x * 128, blockIdx.y * 128, threadIdx.x);
}

// ---------------------------------------------------------------------------
// final: BN finalize (inline from sums) + out = x + relu(bn(t)), x fp32
// ---------------------------------------------------------------------------
__global__ __launch_bounds__(256) void final_kernel(const float* __restrict__ x,
                                                    const short* __restrict__ tbf,
                                                    const float* __restrict__ bnsum,
                                                    const float* __restrict__ bnss,
                                                    const float* __restrict__ gamma,
                                                    const float* __restrict__ beta,
                                                    float* __restrict__ out) {
  const size_t idx = ((size_t)blockIdx.x * 256 + threadIdx.x) << 2;
  const int c = (int)((idx >> 11) & 255);
  const float cnt = (float)(BDIM * NDIM);
  const float mean = bnsum[c] / cnt;
  const float var = fmaxf(bnss[c] / cnt - mean * mean, 0.f);
  const float sc = gamma[c] * rsqrtf(var + 1e-5f);
  const float sh = beta[c] - mean * sc;
  float4 xv = *(const float4*)&x[idx];
  uint2 tu = *(const uint2*)&tbf[idx];
  const float t0 = bflo(tu.x), t1 = bfhi(tu.x), t2 = bflo(tu.y), t3 = bfhi(tu.y);
  float4 r;
  r.x = xv.x + fmaxf(t0 * sc + sh, 0.f);
  r.y = xv.y + fmaxf(t1 * sc + sh, 0.f);
  r.z = xv.z + fmaxf(t2 * sc + sh, 0.f);
  r.w = xv.w + fmaxf(t3 * sc + sh, 0.f);
  *(float4*)&out[idx] = r;
}

extern "C" void kernel_launch(void* const* d_in, const int* in_sizes, int n_in,
                              void* d_out, int out_size, void* d_ws, size_t ws_size,
                              hipStream_t stream) {
  const float* x     = (const float*)d_in[0];
  const float* wq    = (const float*)d_in[1];
  const float* wv    = (const float*)d_in[2];
  const float* bv    = (const float*)d_in[3];
  const float* wt    = (const float*)d_in[4];
  const float* bt    = (const float*)d_in[5];
  const float* gamma = (const float*)d_in[6];
  const float* beta  = (const float*)d_in[7];
  float* out = (float*)d_out;
  char* ws = (char*)d_ws;

  short* xbT   = (short*)(ws);                       // [B][N][C] bf16  8 MB
  short* wqb   = (short*)(ws + ((size_t)9  << 20));  // 32 KB
  short* wvb   = (short*)(ws + ((size_t)9  << 20) + (256 << 10));
  short* wtb   = (short*)(ws + ((size_t)9  << 20) + (512 << 10));
  short* qT    = (short*)(ws + ((size_t)10 << 20));  // [B][N][64] bf16 2 MB
  float* sq2   = (float*)(ws + ((size_t)12 << 20));  // [B][N] f32
  short* vbf   = (short*)(ws + ((size_t)13 << 20));  // [B][C][N] bf16 8 MB
  short* xrT   = (short*)(ws + ((size_t)22 << 20));  // [B][N][C] bf16 8 MB
  short* tbf   = vbf;                                // reuse (v dead after attn)
  float* bnsum = (float*)(ws + ((size_t)31 << 20));  // 256 + 256
  float* bnss  = bnsum + 256;

  prep_kernel<<<dim3(1169), 256, 0, stream>>>(x, wq, wv, wt, xbT, wqb, wvb, wtb, bnsum);
  qv_gemm<<<dim3(512), 256, 0, stream>>>(wqb, wvb, xbT, bv, qT, sq2, vbf);
  attn_mfma<<<dim3(512), 256, 0, stream>>>(qT, vbf, sq2, xrT);
  t_gemm<<<dim3(16, 2, 8), 256, 0, stream>>>(wtb, xrT, bt, tbf, bnsum, bnss);
  final_kernel<<<dim3(4096), 256, 0, stream>>>(x, tbf, bnsum, bnss, gamma, beta, out);
}